// Round 7
// baseline (169.433 us; speedup 1.0000x reference)
//
#include <hip/hip_runtime.h>
#include <hip/hip_bf16.h>

#define NPTS 131072
#define K 27
#define CIN 64
#define COUT 128
#define BM 128                // rows per conv block (8 waves, 4r x 2c)

constexpr float BN_EPS = 1e-5f;
constexpr float NEG_SLOPE = 0.01f;

typedef __attribute__((ext_vector_type(8))) short short8;
typedef __attribute__((ext_vector_type(4))) float f32x4;

__device__ inline unsigned int pk_bf16(float a, float b) {
    __hip_bfloat16 ha = __float2bfloat16(a), hb = __float2bfloat16(b);
    unsigned short ua = *reinterpret_cast<unsigned short*>(&ha);
    unsigned short ub = *reinterpret_cast<unsigned short*>(&hb);
    return (unsigned int)ua | ((unsigned int)ub << 16);
}

// ---------------------------------------------------------------------------
// prep_w: W [27][64][128] f32 -> Wt [27][128][64] bf16
// ---------------------------------------------------------------------------
__global__ __launch_bounds__(256) void prep_w(
    const float* __restrict__ W, unsigned short* __restrict__ Wt)
{
    int o = blockIdx.x * 256 + threadIdx.x;           // 27*128*64 = 221184
    if (o >= K * COUT * CIN) return;
    int k  = o / (COUT * CIN);
    int r  = o % (COUT * CIN);
    int co = r / CIN;
    int ci = r % CIN;
    __hip_bfloat16 h = __float2bfloat16(W[(k * CIN + ci) * COUT + co]);
    Wt[o] = *reinterpret_cast<unsigned short*>(&h);
}

// ---------------------------------------------------------------------------
// prep_f: feats f32 -> bf16 (row NPTS is the zero sentinel, memset'd)
// ---------------------------------------------------------------------------
__global__ __launch_bounds__(256) void prep_f(
    const float* __restrict__ feats, unsigned short* __restrict__ featsb)
{
    size_t t = (size_t)blockIdx.x * 256 + threadIdx.x;   // 1,048,576 threads
    const float4* src = (const float4*)(feats) + t * 2;
    float4 v0 = src[0], v1 = src[1];
    uint4 o;
    o.x = pk_bf16(v0.x, v0.y); o.y = pk_bf16(v0.z, v0.w);
    o.z = pk_bf16(v1.x, v1.y); o.w = pk_bf16(v1.z, v1.w);
    ((uint4*)featsb)[t] = o;
}

// ---------------------------------------------------------------------------
// prep_idx: fold mask into index (masked-off -> sentinel zero row NPTS)
// ---------------------------------------------------------------------------
__global__ __launch_bounds__(256) void prep_idx(
    const int* __restrict__ nidx, const int* __restrict__ nmask,
    int* __restrict__ midx)
{
    int t = blockIdx.x * 256 + threadIdx.x;              // 3,538,944
    if (t < NPTS * K) midx[t] = nmask[t] ? nidx[t] : NPTS;
}

// ---------------------------------------------------------------------------
// conv: A-fragments gathered DIRECTLY from global (L3-resident featsb) into
// registers -- A never touches LDS.  B double-buffered in LDS with ONE
// barrier per k-iteration.  512 thr = 8 waves (4r x 2c), 128x128 out tile.
// ---------------------------------------------------------------------------
template<bool MIDX>
__global__ __launch_bounds__(512) void conv_kernel(
    const unsigned short* __restrict__ featsb,   // NPTS+1 rows (last = zeros)
    const int* __restrict__ midx,                // if MIDX
    const int* __restrict__ nidx,                // else
    const int* __restrict__ nmask,
    const unsigned short* __restrict__ Wt,
    float* __restrict__ y,
    float* __restrict__ accum)                   // [256]: sums then sumsqs
{
    __shared__ unsigned char Blds[2][COUT * CIN * 2];    // 2 x 16 KB

    const int tid  = threadIdx.x;
    const int l    = tid & 63;
    const int wid  = tid >> 6;        // 0..7
    const int wr   = wid >> 1;        // 0..3  (32 rows each)
    const int wc   = wid & 1;         // 0..1  (64 cols each)
    const int base = blockIdx.x * BM;

    // B staging role: 4 threads per col, 32 B each (coalesced from Wt)
    const int bcol = tid >> 2;
    const int bq   = tid & 3;
    const int bswz = (bcol & 7) << 4;

    const unsigned char* fb = (const unsigned char*)featsb;   // 128 B rows
    const int abyte = (l >> 4) * 16;                 // fragment byte-of-row
    const int arow0 = base + wr * 32 + (l & 15);     // m=0 row; m=1 -> +16

    auto loadIdx = [&](int kq, int m) -> int {
        kq = kq < K ? kq : K - 1;                    // clamp: harmless
        int o = (arow0 + m * 16) * K + kq;
        if constexpr (MIDX) return midx[o];
        else                return nmask[o] ? nidx[o] : NPTS;
    };

    // A fragment regs: two named sets (even/odd iter), static indexing
    short8 a0[2][2], a1[2][2];        // [m][ks]
    uint4  bB0, bB1;                  // B staging regs (32 B / thread)
    int    j0, j1;                    // ids for the next LOAD_A

#define LOAD_A(A, i0, i1)                                                     \
    { A[0][0] = *(const short8*)(fb + (size_t)(i0) * 128 + abyte);            \
      A[0][1] = *(const short8*)(fb + (size_t)(i0) * 128 + abyte + 64);       \
      A[1][0] = *(const short8*)(fb + (size_t)(i1) * 128 + abyte);            \
      A[1][1] = *(const short8*)(fb + (size_t)(i1) * 128 + abyte + 64); }

#define ISSUE_B(kq)                                                           \
    { int kk_ = (kq) < K ? (kq) : K - 1;                                      \
      const uint4* p_ = (const uint4*)(Wt + ((size_t)kk_ * COUT + bcol) * CIN) + bq * 2; \
      bB0 = p_[0]; bB1 = p_[1]; }

#define WRITE_B(BUF)                                                          \
    { unsigned char* bp_ = (unsigned char*)Blds[BUF] + bcol * 128;            \
      *(uint4*)(bp_ + ((bq * 32     ) ^ bswz)) = bB0;                         \
      *(uint4*)(bp_ + ((bq * 32 + 16) ^ bswz)) = bB1; }

    f32x4 acc[2][4];
#pragma unroll
    for (int m = 0; m < 2; ++m)
#pragma unroll
        for (int n = 0; n < 4; ++n) acc[m][n] = (f32x4)0.f;

#define MFMA_TILE(BUF, A)                                                     \
    _Pragma("unroll")                                                         \
    for (int ks = 0; ks < 2; ++ks) {                                          \
        short8 bfr[4];                                                        \
        _Pragma("unroll")                                                     \
        for (int n = 0; n < 4; ++n) {                                         \
            int col = wc * 64 + n * 16 + (l & 15);                            \
            bfr[n] = *(const short8*)((unsigned char*)Blds[BUF] + col * 128   \
                        + ((ks * 64 + abyte) ^ ((col & 7) << 4)));            \
        }                                                                     \
        _Pragma("unroll")                                                     \
        for (int m = 0; m < 2; ++m)                                           \
            _Pragma("unroll")                                                 \
            for (int n = 0; n < 4; ++n)                                       \
                acc[m][n] = __builtin_amdgcn_mfma_f32_16x16x32_bf16(          \
                    A[m][ks], bfr[n], acc[m][n], 0, 0, 0);                    \
    }

    // ---- prologue: A(0) in flight, B(0) staged, B(1) issued, idx(1) ----
    {
        int i00 = loadIdx(0, 0), i01 = loadIdx(0, 1);
        LOAD_A(a0, i00, i01);
        ISSUE_B(0);
        j0 = loadIdx(1, 0); j1 = loadIdx(1, 1);
        WRITE_B(0);                    // waits bB regs only
        ISSUE_B(1);
        __syncthreads();               // buf0 visible
    }

    // ---- main loop: pairs (k even, k+1 odd), k = 0,2,...,24 ----
    for (int k = 0; k < K - 1; k += 2) {
        // even iter k: uses a0, buf[k&1]=buf0
        LOAD_A(a1, j0, j1);            // A(k+1)
        j0 = loadIdx(k + 2, 0); j1 = loadIdx(k + 2, 1);
        MFMA_TILE(0, a0);
        WRITE_B(1);                    // B(k+1) -> buf1 (last read in k-1)
        ISSUE_B(k + 2);
        __syncthreads();

        // odd iter k+1: uses a1, buf1
        LOAD_A(a0, j0, j1);            // A(k+2)
        j0 = loadIdx(k + 3, 0); j1 = loadIdx(k + 3, 1);
        MFMA_TILE(1, a1);
        WRITE_B(0);                    // B(k+2) -> buf0
        ISSUE_B(k + 3);
        __syncthreads();
    }
    // ---- tail iter k = 26: buf[26&1]=buf0, a0 = A(26) ----
    MFMA_TILE(0, a0);

    // ---- y write: C/D layout col=l&15, row=(l>>4)*4+r ----
#pragma unroll
    for (int m = 0; m < 2; ++m)
#pragma unroll
        for (int n = 0; n < 4; ++n) {
            int gcol = wc * 64 + n * 16 + (l & 15);
#pragma unroll
            for (int r = 0; r < 4; ++r) {
                int grow = base + wr * 32 + m * 16 + (l >> 4) * 4 + r;
                y[(size_t)grow * COUT + gcol] = acc[m][n][r];
            }
        }

    // ---- fused per-block BN stats (reuse Blds as combine buffer) ----
    float sv[4], s2v[4];
#pragma unroll
    for (int n = 0; n < 4; ++n) {
        float s = 0.f, s2 = 0.f;
#pragma unroll
        for (int m = 0; m < 2; ++m)
#pragma unroll
            for (int r = 0; r < 4; ++r) { float v = acc[m][n][r]; s += v; s2 += v * v; }
        s  += __shfl_xor(s, 16);  s  += __shfl_xor(s, 32);
        s2 += __shfl_xor(s2, 16); s2 += __shfl_xor(s2, 32);
        sv[n] = s; s2v[n] = s2;
    }
    __syncthreads();                  // all MFMA reads of Blds done
    float* statf = (float*)Blds[0];   // [2][4][128] = 4 KB
    if (l < 16) {
#pragma unroll
        for (int n = 0; n < 4; ++n) {
            int c = wc * 64 + n * 16 + l;
            statf[(0 * 4 + wr) * 128 + c] = sv[n];
            statf[(1 * 4 + wr) * 128 + c] = s2v[n];
        }
    }
    __syncthreads();
    if (tid < 128) {
        float s  = statf[0 * 128 + tid] + statf[1 * 128 + tid]
                 + statf[2 * 128 + tid] + statf[3 * 128 + tid];
        float s2 = statf[4 * 128 + tid] + statf[5 * 128 + tid]
                 + statf[6 * 128 + tid] + statf[7 * 128 + tid];
        atomicAdd(&accum[tid], s);
        atomicAdd(&accum[128 + tid], s2);
    }
#undef LOAD_A
#undef ISSUE_B
#undef WRITE_B
#undef MFMA_TILE
}

// ---------------------------------------------------------------------------
// finalize: fold mean/var/gamma/beta into per-channel scale+bias
// ---------------------------------------------------------------------------
__global__ void finalize_kernel(const float* __restrict__ accum,
                                const float* __restrict__ gamma,
                                const float* __restrict__ beta,
                                float* __restrict__ sb)
{
    int c = threadIdx.x;                      // 128 threads
    float invN  = 1.0f / (float)NPTS;
    float mean  = accum[c] * invN;
    float var   = accum[128 + c] * invN - mean * mean;
    float scale = gamma[c] * rsqrtf(var + BN_EPS);
    sb[c]       = scale;
    sb[128 + c] = beta[c] - mean * scale;
}

// ---------------------------------------------------------------------------
// bn: y = leaky(y*scale+bias), float4-vectorized, scale/bias in registers
// ---------------------------------------------------------------------------
__global__ __launch_bounds__(256) void bn_kernel(
    float* __restrict__ y, const float* __restrict__ sb)
{
    size_t start = (size_t)blockIdx.x * blockDim.x + threadIdx.x;
    int c0 = (int)((start * 4) & (COUT - 1));   // invariant under grid stride
    float sc[4], bi[4];
#pragma unroll
    for (int j = 0; j < 4; ++j) { sc[j] = sb[c0 + j]; bi[j] = sb[COUT + c0 + j]; }

    const size_t total = (size_t)NPTS * COUT / 4;
    const size_t step  = (size_t)gridDim.x * blockDim.x;
    for (size_t idx = start; idx < total; idx += step) {
        float4 v = ((const float4*)y)[idx];
        v.x = v.x * sc[0] + bi[0]; v.x = v.x > 0.f ? v.x : NEG_SLOPE * v.x;
        v.y = v.y * sc[1] + bi[1]; v.y = v.y > 0.f ? v.y : NEG_SLOPE * v.y;
        v.z = v.z * sc[2] + bi[2]; v.z = v.z > 0.f ? v.z : NEG_SLOPE * v.z;
        v.w = v.w * sc[3] + bi[3]; v.w = v.w > 0.f ? v.w : NEG_SLOPE * v.w;
        ((float4*)y)[idx] = v;
    }
}

extern "C" void kernel_launch(void* const* d_in, const int* in_sizes, int n_in,
                              void* d_out, int out_size, void* d_ws, size_t ws_size,
                              hipStream_t stream)
{
    const float* feats = (const float*)d_in[0];
    const int*   nidx  = (const int*)d_in[1];
    const int*   nmask = (const int*)d_in[2];
    const float* W     = (const float*)d_in[3];
    const float* gamma = (const float*)d_in[4];
    const float* beta  = (const float*)d_in[5];

    float* y = (float*)d_out;

    // ws layout
    float*          accum  = (float*)d_ws;                               // 1 KB
    float*          sb     = (float*)((char*)d_ws + 1024);               // 1 KB
    unsigned short* Wt     = (unsigned short*)((char*)d_ws + 4096);      // 442 KB
    unsigned short* featsb = (unsigned short*)((char*)d_ws + 458752);    // 16.78 MB (NPTS+1 rows)
    int*            midx   = (int*)((char*)d_ws + 17236224);             // 14.16 MB
    const size_t need_midx = 17236224 + (size_t)NPTS * K * sizeof(int);
    const bool use_midx = ws_size >= need_midx;

    hipMemsetAsync(accum, 0, 2 * COUT * sizeof(float), stream);
    hipMemsetAsync(featsb + (size_t)NPTS * CIN, 0, CIN * 2, stream);   // zero sentinel row

    prep_w<<<(K * COUT * CIN + 255) / 256, 256, 0, stream>>>(W, Wt);
    prep_f<<<(NPTS * CIN / 8) / 256, 256, 0, stream>>>(feats, featsb);
    if (use_midx) {
        prep_idx<<<(NPTS * K + 255) / 256, 256, 0, stream>>>(nidx, nmask, midx);
        conv_kernel<true><<<NPTS / BM, 512, 0, stream>>>(featsb, midx, nidx, nmask, Wt, y, accum);
    } else {
        conv_kernel<false><<<NPTS / BM, 512, 0, stream>>>(featsb, midx, nidx, nmask, Wt, y, accum);
    }
    finalize_kernel<<<1, 128, 0, stream>>>(accum, gamma, beta, sb);
    bn_kernel<<<2048, 256, 0, stream>>>(y, sb);
}

// Round 8
// 161.817 us; speedup vs baseline: 1.0471x; 1.0471x over previous
//
#include <hip/hip_runtime.h>
#include <hip/hip_bf16.h>

#define NPTS 131072
#define K 27
#define CIN 64
#define COUT 128
#define BM 64                 // rows per conv block
#define NQ 54                 // 2 halves x 27 offsets

constexpr float BN_EPS = 1e-5f;
constexpr float NEG_SLOPE = 0.01f;

typedef __attribute__((ext_vector_type(8))) short short8;
typedef __attribute__((ext_vector_type(4))) float f32x4;

__device__ inline unsigned int pk_bf16(float a, float b) {
    __hip_bfloat16 ha = __float2bfloat16(a), hb = __float2bfloat16(b);
    unsigned short ua = *reinterpret_cast<unsigned short*>(&ha);
    unsigned short ub = *reinterpret_cast<unsigned short*>(&hb);
    return (unsigned int)ua | ((unsigned int)ub << 16);
}

// ---------------------------------------------------------------------------
// prep_w: W [27][64][128] f32 -> Wt2 [27][half][128][32] bf16
// ---------------------------------------------------------------------------
__global__ __launch_bounds__(256) void prep_w(
    const float* __restrict__ W, unsigned short* __restrict__ Wt2)
{
    int o = blockIdx.x * 256 + threadIdx.x;           // 221184
    if (o >= K * COUT * CIN) return;
    int k  = o / (COUT * CIN);
    int r  = o % (COUT * CIN);
    int co = r / CIN;
    int ci = r % CIN;
    __hip_bfloat16 h = __float2bfloat16(W[(k * CIN + ci) * COUT + co]);
    int half = ci >> 5;
    Wt2[(((k * 2 + half) * COUT) + co) * 32 + (ci & 31)] =
        *reinterpret_cast<unsigned short*>(&h);
}

// ---------------------------------------------------------------------------
// prep_f: feats f32 -> two bf16 half-tables (lo = ch 0..31, hi = ch 32..63),
// each (NPTS+1) rows x 64 B; row NPTS is the zero sentinel (memset'd).
// ---------------------------------------------------------------------------
__global__ __launch_bounds__(256) void prep_f(
    const float* __restrict__ feats,
    unsigned char* __restrict__ flo, unsigned char* __restrict__ fhi)
{
    size_t t = (size_t)blockIdx.x * 256 + threadIdx.x;   // 1,048,576
    size_t row = t >> 3;
    int    c0  = (int)(t & 7) * 8;
    const float4* src = (const float4*)(feats + row * CIN + c0);
    float4 v0 = src[0], v1 = src[1];
    uint4 o;
    o.x = pk_bf16(v0.x, v0.y); o.y = pk_bf16(v0.z, v0.w);
    o.z = pk_bf16(v1.x, v1.y); o.w = pk_bf16(v1.z, v1.w);
    unsigned char* tb = (c0 < 32) ? flo : fhi;
    *(uint4*)(tb + row * 64 + (c0 & 31) * 2) = o;
}

// ---------------------------------------------------------------------------
// prep_idx: fold mask into index (masked-off -> sentinel zero row NPTS)
// ---------------------------------------------------------------------------
__global__ __launch_bounds__(256) void prep_idx(
    const int* __restrict__ nidx, const int* __restrict__ nmask,
    int* __restrict__ midx)
{
    int t = blockIdx.x * 256 + threadIdx.x;              // 3,538,944
    if (t < NPTS * K) midx[t] = nmask[t] ? nidx[t] : NPTS;
}

// ---------------------------------------------------------------------------
// conv: CIN-phase-split MFMA gather-conv.  54 iterations (27 k-offsets x 2
// channel-halves), instantaneous gather footprint = one 8.4 MB half-table
// (vs 16.8 MB) -> higher L2 hit rate on the random gather.  2-deep A
// register prefetch; LDS rows padded to 80 B (2-way-free banks, no XOR).
// ---------------------------------------------------------------------------
template<bool MIDX>
__global__ __launch_bounds__(256) void conv_kernel(
    const unsigned char* __restrict__ flo,   // (NPTS+1) x 64 B
    const unsigned char* __restrict__ fhi,
    const int* __restrict__ midx,            // if MIDX
    const int* __restrict__ nidx,            // else
    const int* __restrict__ nmask,
    const unsigned char* __restrict__ Wt2,   // [27][2][128][32] bf16
    float* __restrict__ y,
    float* __restrict__ accum)               // [256]: sums then sumsqs
{
    __shared__ unsigned char Alds[BM * 80];       // 5 KB
    __shared__ unsigned char Blds[COUT * 80];     // 10 KB

    const int tid  = threadIdx.x;
    const int l    = tid & 63;
    const int wid  = tid >> 6;
    const int wr   = wid >> 1;        // 0..1 (32 rows each)
    const int wc   = wid & 1;         // 0..1 (64 cols each)
    const int base = blockIdx.x * BM;

    const int arow = tid >> 2;        // 4 thr/row, 16 B each
    const int aq   = tid & 3;
    const int bcol = tid >> 1;        // 2 thr/col, 32 B each
    const int bq   = tid & 1;

    auto loadIdx = [&](int q) -> int {
        int qq = q < NQ ? q : NQ - 1;
        int k  = qq < K ? qq : qq - K;
        int o  = (base + arow) * K + k;
        if constexpr (MIDX) return midx[o];
        else                return nmask[o] ? nidx[o] : NPTS;
    };

    unsigned char* ap = Alds + arow * 80;
    unsigned char* bp = Blds + bcol * 80;

    uint4 aA, aB;                     // A staging regs (16 B each), 2-deep
    uint4 b0, b1;                     // B staging regs (32 B)
    int   idE, idO;

#define ISSUE_A(qn, id, x)                                                    \
    { const unsigned char* tb_ = ((qn) < K ? flo : fhi);                      \
      x = *(const uint4*)(tb_ + (size_t)(id) * 64 + aq * 16); }

#define ISSUE_B(q)                                                            \
    { int qq_ = (q) < NQ ? (q) : NQ - 1;                                      \
      int k2h_ = qq_ < K ? qq_ * 2 : (qq_ - K) * 2 + 1;                       \
      const uint4* p_ = (const uint4*)(Wt2 + ((size_t)k2h_ * COUT + bcol) * 64 + bq * 32); \
      b0 = p_[0]; b1 = p_[1]; }

#define WRITE_A(x)  { *(uint4*)(ap + aq * 16) = x; }
#define WRITE_B()   { *(uint4*)(bp + bq * 32) = b0;                           \
                      *(uint4*)(bp + bq * 32 + 16) = b1; }

    f32x4 acc[2][4];
#pragma unroll
    for (int m = 0; m < 2; ++m)
#pragma unroll
        for (int n = 0; n < 4; ++n) acc[m][n] = (f32x4)0.f;

#define MFMA_TILE()                                                           \
    {                                                                         \
        short8 afr[2], bfr[4];                                                \
        _Pragma("unroll")                                                     \
        for (int m = 0; m < 2; ++m) {                                         \
            int row = wr * 32 + m * 16 + (l & 15);                            \
            afr[m] = *(const short8*)(Alds + row * 80 + (l >> 4) * 16);       \
        }                                                                     \
        _Pragma("unroll")                                                     \
        for (int n = 0; n < 4; ++n) {                                         \
            int col = wc * 64 + n * 16 + (l & 15);                            \
            bfr[n] = *(const short8*)(Blds + col * 80 + (l >> 4) * 16);       \
        }                                                                     \
        _Pragma("unroll")                                                     \
        for (int m = 0; m < 2; ++m)                                           \
            _Pragma("unroll")                                                 \
            for (int n = 0; n < 4; ++n)                                       \
                acc[m][n] = __builtin_amdgcn_mfma_f32_16x16x32_bf16(          \
                    afr[m], bfr[n], acc[m][n], 0, 0, 0);                      \
    }

    // ---- prologue: A(0), A(1), B(0) in flight; ids for q=2,3 ----
    {
        int id0 = loadIdx(0);
        int id1 = loadIdx(1);
        ISSUE_A(0, id0, aA);
        ISSUE_A(1, id1, aB);
        ISSUE_B(0);
        idE = loadIdx(2);
        idO = loadIdx(3);
    }

    // ---- main loop: 27 pairs (q even, q odd), q = 0,2,...,52 ----
    for (int q = 0; q < NQ; q += 2) {
        // even iter q
        __syncthreads();
        WRITE_A(aA);
        WRITE_B();
        ISSUE_A(q + 2, idE, aA);       // A(q+2)
        ISSUE_B(q + 1);
        idE = loadIdx(q + 4);
        __syncthreads();
        MFMA_TILE();

        // odd iter q+1
        __syncthreads();
        WRITE_A(aB);
        WRITE_B();
        ISSUE_A(q + 3, idO, aB);       // A(q+3)
        ISSUE_B(q + 2);
        idO = loadIdx(q + 5);
        __syncthreads();
        MFMA_TILE();
    }

    // ---- y write (nontemporal: don't evict the gather table from L2) ----
#pragma unroll
    for (int m = 0; m < 2; ++m)
#pragma unroll
        for (int n = 0; n < 4; ++n) {
            int gcol = wc * 64 + n * 16 + (l & 15);
#pragma unroll
            for (int r = 0; r < 4; ++r) {
                int grow = base + wr * 32 + m * 16 + (l >> 4) * 4 + r;
                __builtin_nontemporal_store(acc[m][n][r],
                                            &y[(size_t)grow * COUT + gcol]);
            }
        }

    // ---- fused per-block BN stats (reuse Alds as combine buffer) ----
    float sv[4], s2v[4];
#pragma unroll
    for (int n = 0; n < 4; ++n) {
        float s = 0.f, s2 = 0.f;
#pragma unroll
        for (int m = 0; m < 2; ++m)
#pragma unroll
            for (int r = 0; r < 4; ++r) { float v = acc[m][n][r]; s += v; s2 += v * v; }
        s  += __shfl_xor(s, 16);  s  += __shfl_xor(s, 32);
        s2 += __shfl_xor(s2, 16); s2 += __shfl_xor(s2, 32);
        sv[n] = s; s2v[n] = s2;
    }
    __syncthreads();                  // all MFMA reads of Alds done
    float* statf = (float*)Alds;      // [2][2][128] = 4 KB (fits in 5 KB)
    if (l < 16) {
#pragma unroll
        for (int n = 0; n < 4; ++n) {
            int c = wc * 64 + n * 16 + l;
            statf[(0 * 2 + wr) * 128 + c] = sv[n];
            statf[(1 * 2 + wr) * 128 + c] = s2v[n];
        }
    }
    __syncthreads();
    if (tid < 128) {
        atomicAdd(&accum[tid],       statf[0 * 128 + tid] + statf[1 * 128 + tid]);
        atomicAdd(&accum[128 + tid], statf[2 * 128 + tid] + statf[3 * 128 + tid]);
    }
#undef ISSUE_A
#undef ISSUE_B
#undef WRITE_A
#undef WRITE_B
#undef MFMA_TILE
}

// ---------------------------------------------------------------------------
// finalize: fold mean/var/gamma/beta into per-channel scale+bias
// ---------------------------------------------------------------------------
__global__ void finalize_kernel(const float* __restrict__ accum,
                                const float* __restrict__ gamma,
                                const float* __restrict__ beta,
                                float* __restrict__ sb)
{
    int c = threadIdx.x;                      // 128 threads
    float invN  = 1.0f / (float)NPTS;
    float mean  = accum[c] * invN;
    float var   = accum[128 + c] * invN - mean * mean;
    float scale = gamma[c] * rsqrtf(var + BN_EPS);
    sb[c]       = scale;
    sb[128 + c] = beta[c] - mean * scale;
}

// ---------------------------------------------------------------------------
// bn: y = leaky(y*scale+bias), float4-vectorized, scale/bias in registers
// ---------------------------------------------------------------------------
__global__ __launch_bounds__(256) void bn_kernel(
    float* __restrict__ y, const float* __restrict__ sb)
{
    size_t start = (size_t)blockIdx.x * blockDim.x + threadIdx.x;
    int c0 = (int)((start * 4) & (COUT - 1));   // invariant under grid stride
    float sc[4], bi[4];
#pragma unroll
    for (int j = 0; j < 4; ++j) { sc[j] = sb[c0 + j]; bi[j] = sb[COUT + c0 + j]; }

    const size_t total = (size_t)NPTS * COUT / 4;
    const size_t step  = (size_t)gridDim.x * blockDim.x;
    for (size_t idx = start; idx < total; idx += step) {
        float4 v = ((const float4*)y)[idx];
        v.x = v.x * sc[0] + bi[0]; v.x = v.x > 0.f ? v.x : NEG_SLOPE * v.x;
        v.y = v.y * sc[1] + bi[1]; v.y = v.y > 0.f ? v.y : NEG_SLOPE * v.y;
        v.z = v.z * sc[2] + bi[2]; v.z = v.z > 0.f ? v.z : NEG_SLOPE * v.z;
        v.w = v.w * sc[3] + bi[3]; v.w = v.w > 0.f ? v.w : NEG_SLOPE * v.w;
        ((float4*)y)[idx] = v;
    }
}

extern "C" void kernel_launch(void* const* d_in, const int* in_sizes, int n_in,
                              void* d_out, int out_size, void* d_ws, size_t ws_size,
                              hipStream_t stream)
{
    const float* feats = (const float*)d_in[0];
    const int*   nidx  = (const int*)d_in[1];
    const int*   nmask = (const int*)d_in[2];
    const float* W     = (const float*)d_in[3];
    const float* gamma = (const float*)d_in[4];
    const float* beta  = (const float*)d_in[5];

    float* y = (float*)d_out;

    // ws layout (bytes)
    float*          accum = (float*)d_ws;                                // 1 KB
    float*          sb    = (float*)((char*)d_ws + 1024);                // 1 KB
    unsigned short* Wt2   = (unsigned short*)((char*)d_ws + 4096);       // 432 KB
    unsigned char*  flo   = (unsigned char*)d_ws + 458752;               // 8.39 MB
    unsigned char*  fhi   = flo + (size_t)(NPTS + 1) * 64;               // 8.39 MB
    int*            midx  = (int*)(fhi + (size_t)(NPTS + 1) * 64);       // 14.16 MB
    const size_t need = (458752 + 2 * (size_t)(NPTS + 1) * 64
                         + (size_t)NPTS * K * sizeof(int));
    const bool use_midx = ws_size >= need;

    hipMemsetAsync(accum, 0, 2 * COUT * sizeof(float), stream);
    hipMemsetAsync(flo + (size_t)NPTS * 64, 0, 64, stream);   // zero sentinels
    hipMemsetAsync(fhi + (size_t)NPTS * 64, 0, 64, stream);

    prep_w<<<(K * COUT * CIN + 255) / 256, 256, 0, stream>>>(W, Wt2);
    prep_f<<<(NPTS * CIN / 8) / 256, 256, 0, stream>>>(feats, flo, fhi);
    if (use_midx) {
        prep_idx<<<(NPTS * K + 255) / 256, 256, 0, stream>>>(nidx, nmask, midx);
        conv_kernel<true><<<NPTS / BM, 256, 0, stream>>>(flo, fhi, midx, nidx, nmask,
                                                         (const unsigned char*)Wt2, y, accum);
    } else {
        conv_kernel<false><<<NPTS / BM, 256, 0, stream>>>(flo, fhi, midx, nidx, nmask,
                                                          (const unsigned char*)Wt2, y, accum);
    }
    finalize_kernel<<<1, 128, 0, stream>>>(accum, gamma, beta, sb);
    bn_kernel<<<2048, 256, 0, stream>>>(y, sb);
}